// Round 7
// baseline (2490.193 us; speedup 1.0000x reference)
//
#include <hip/hip_runtime.h>
#include <cstdint>

typedef unsigned short u16;
typedef unsigned int   u32;

typedef short bf16x8 __attribute__((ext_vector_type(8)));
typedef float f32x4  __attribute__((ext_vector_type(4)));

#define MFMA(a,b,c) __builtin_amdgcn_mfma_f32_16x16x32_bf16(a,b,c,0,0,0)

// async global->LDS, 16B per lane: LDS dest = wave-uniform base + lane*16,
// global src = per-lane address (guide §5, m97/m104)
#define GLD16(g, s) __builtin_amdgcn_global_load_lds(                      \
    (const __attribute__((address_space(1))) void*)(g),                    \
    (__attribute__((address_space(3))) void*)(s), 16, 0, 0)

__device__ __forceinline__ u16 f2b(float f) {
  u32 u = __float_as_uint(f);
  u += 0x7FFFu + ((u >> 16) & 1u);
  return (u16)(u >> 16);
}

// ---------------- weight transpose + cast: W[K][N] f32 -> WT[N][K] bf16 ----
__global__ __launch_bounds__(256) void transp_k(const float* __restrict__ W,
                                                u16* __restrict__ WT, int K, int N) {
  __shared__ float t[32][33];
  int tx = threadIdx.x & 31, ty = threadIdx.x >> 5;
  long bo = (long)blockIdx.z * K * N;
  int n0 = blockIdx.x * 32, k0 = blockIdx.y * 32;
  const float* Wp = W + bo;
  u16* Tp = WT + bo;
#pragma unroll
  for (int i = 0; i < 32; i += 8)
    t[ty + i][tx] = Wp[(long)(k0 + ty + i) * N + n0 + tx];
  __syncthreads();
#pragma unroll
  for (int i = 0; i < 32; i += 8)
    Tp[(long)(n0 + ty + i) * K + k0 + tx] = f2b(t[tx][ty + i]);
}

// ---------------- patchify: pixels -> patA[16384][768] bf16 ----------------
__global__ __launch_bounds__(256) void patchify_k(const float* __restrict__ pix,
                                                  u16* __restrict__ patA) {
  int idx = blockIdx.x * 256 + threadIdx.x;        // 12,582,912 total (exact)
  int x = idx & 1023;
  int y = (idx >> 10) & 63;
  int c = (idx >> 16) % 3;
  int b = idx / 196608;
  int p  = ((y >> 4) << 6) | (x >> 4);             // ph*64 + pw
  int ci = (c << 8) | ((y & 15) << 4) | (x & 15);  // c*256 + py*16 + px
  patA[(long)(b * 256 + p) * 768 + ci] = f2b(pix[idx]);
}

// ---------------- cls row fill ---------------------------------------------
__global__ __launch_bounds__(256) void cls_k(const float* __restrict__ cls,
                                             float* __restrict__ xF) {
  int i = blockIdx.x * 256 + threadIdx.x;          // 32768 total
  int b = i >> 9, n = i & 511;
  xF[(long)(b * 257) * 512 + n] = cls[n];
}

// ---------------- LayerNorm rows of 512: f32 in -> bf16 (OUT=0) / f32 (OUT=1)
template <int OUT>
__global__ __launch_bounds__(256) void ln_k(const float* __restrict__ x,
                                            const float* __restrict__ gm,
                                            const float* __restrict__ bt,
                                            u16* __restrict__ outB,
                                            float* __restrict__ outF) {
  int row = blockIdx.x * 4 + (threadIdx.x >> 6);
  int l = threadIdx.x & 63;
  const float* xr = x + (long)row * 512 + l * 8;
  float v[8];
  *(float4*)(v)     = *(const float4*)(xr);
  *(float4*)(v + 4) = *(const float4*)(xr + 4);
  float s = 0.f, s2 = 0.f;
#pragma unroll
  for (int j = 0; j < 8; ++j) { s += v[j]; s2 += v[j] * v[j]; }
#pragma unroll
  for (int xm = 1; xm < 64; xm <<= 1) {
    s  += __shfl_xor(s, xm);
    s2 += __shfl_xor(s2, xm);
  }
  float m   = s * (1.f / 512.f);
  float var = fmaxf(s2 * (1.f / 512.f) - m * m, 0.f);
  float rs  = rsqrtf(var + 1e-5f);
  if (OUT == 0) {
    u16 o8[8];
#pragma unroll
    for (int j = 0; j < 8; ++j)
      o8[j] = f2b((v[j] - m) * rs * gm[l * 8 + j] + bt[l * 8 + j]);
    *(uint4*)&outB[(long)row * 512 + l * 8] = *(const uint4*)o8;
  } else {
    float o8[8];
#pragma unroll
    for (int j = 0; j < 8; ++j)
      o8[j] = (v[j] - m) * rs * gm[l * 8 + j] + bt[l * 8 + j];
    float* op = outF + (long)row * 512 + l * 8;
    *(float4*)(op)     = *(const float4*)(o8);
    *(float4*)(op + 4) = *(const float4*)(o8 + 4);
  }
}

// ---------------- GEMM: C[M][N] = A[M][K]bf16 * Bt[N][K]bf16 + epilogue ----
// Staging via global_load_lds width=16 (async DMA, no VGPR round-trip).
// LDS layout: chunk ch (16B) at byte offset ch*16 == row (ch>>2) * 64B + (ch&3)*16B.
// Wave w lane l stages chunks w*128+l and w*128+64+l of each matrix.
// EPI 0: patch (bias + 2D pos-emb, remap rows, f32 out)
// EPI 1: bias -> bf16 out
// EPI 2: bias + residual -> f32 out
// EPI 3: bias + exact GELU -> bf16 out
// EPI 4: bias -> f32 out
template <int EPI>
__global__ __launch_bounds__(256) void gemm_k(
    const u16* __restrict__ A, const u16* __restrict__ Bt,
    const float* __restrict__ bias, const float* __restrict__ res,
    float* __restrict__ outF, u16* __restrict__ outB,
    int N, int K, int Mreal,
    const float* __restrict__ aux1, const float* __restrict__ aux2) {
  __shared__ u16 As[128 * 32];
  __shared__ u16 Bs[128 * 32];
  int tid = threadIdx.x, w = tid >> 6, l = tid & 63, g = l >> 4, c = l & 15;
  int mt = blockIdx.y, nt = blockIdx.x;
  int wr = (w >> 1) * 64, wc = (w & 1) * 64;
  f32x4 zero = {0.f, 0.f, 0.f, 0.f};
  f32x4 acc[4][4];
#pragma unroll
  for (int m = 0; m < 4; ++m)
#pragma unroll
    for (int n = 0; n < 4; ++n) acc[m][n] = zero;

  // per-lane global element offsets for the two staged chunks
  int c0 = w * 128 + l;
  int c1 = c0 + 64;
  long gOff0 = (long)(c0 >> 2) * K + (c0 & 3) * 8;
  long gOff1 = (long)(c1 >> 2) * K + (c1 & 3) * 8;
  // wave-uniform LDS bases (u16 index: chunk*8)
  u16* lA0 = &As[(w * 128) * 8];
  u16* lA1 = &As[(w * 128 + 64) * 8];
  u16* lB0 = &Bs[(w * 128) * 8];
  u16* lB1 = &Bs[(w * 128 + 64) * 8];
  const u16* Ab = A + (long)(mt * 128) * K;
  const u16* Bb = Bt + (long)(nt * 128) * K;

  for (int k0 = 0; k0 < K; k0 += 32) {
    __syncthreads();                    // prior compute done; LDS reusable
    GLD16(Ab + gOff0 + k0, lA0);
    GLD16(Ab + gOff1 + k0, lA1);
    GLD16(Bb + gOff0 + k0, lB0);
    GLD16(Bb + gOff1 + k0, lB1);
    __syncthreads();                    // drains vmcnt(0): staged data visible
    bf16x8 af[4], bfr[4];
#pragma unroll
    for (int m = 0; m < 4; ++m)
      af[m] = *(const bf16x8*)&As[(wr + m * 16 + c) * 32 + g * 8];
#pragma unroll
    for (int n = 0; n < 4; ++n)
      bfr[n] = *(const bf16x8*)&Bs[(wc + n * 16 + c) * 32 + g * 8];
#pragma unroll
    for (int m = 0; m < 4; ++m)
#pragma unroll
      for (int n = 0; n < 4; ++n)
        acc[m][n] = MFMA(af[m], bfr[n], acc[m][n]);
  }

  long Nl = N;
#pragma unroll
  for (int m = 0; m < 4; ++m) {
    int rbase = mt * 128 + wr + m * 16 + g * 4;
#pragma unroll
    for (int n = 0; n < 4; ++n) {
      int col = nt * 128 + wc + n * 16 + c;
      float bv = bias[col];
#pragma unroll
      for (int q = 0; q < 4; ++q) {
        int row = rbase + q;
        if (row >= Mreal) continue;
        float v = acc[m][n][q] + bv;
        if (EPI == 0) {
          int pb = row >> 8, p = row & 255;
          float pos = (col < 256) ? aux1[(p >> 6) * 256 + col]
                                  : aux2[(p & 63) * 256 + col - 256];
          outF[(long)(pb * 257 + 1 + p) * 512 + col] = v + pos;
        } else if (EPI == 1) {
          outB[(long)row * Nl + col] = f2b(v);
        } else if (EPI == 2) {
          outF[(long)row * Nl + col] = res[(long)row * Nl + col] + v;
        } else if (EPI == 3) {
          float gv = v * 0.5f * (1.0f + erff(v * 0.70710678118f));
          outB[(long)row * Nl + col] = f2b(gv);
        } else {
          outF[(long)row * Nl + col] = v;
        }
      }
    }
  }
}

// ---------------- attention part A: scores + softmax -> P ------------------
// grid: (B*NH)*5 blocks; block 256 (4 waves, 16 q-rows each)
// P layout: [bh][272 q][288 k] bf16
__global__ __launch_bounds__(256) void attn_scores_k(const u16* __restrict__ qkv,
                                                     u16* __restrict__ P) {
  __shared__ u16 Kl[272 * 72];
  int bx = blockIdx.x;
  int bh = bx / 5, qb = bx % 5;
  int b = bh >> 3, h = bh & 7;
  int tid = threadIdx.x, w = tid >> 6, l = tid & 63, g = l >> 4, c = l & 15;
  long qkvbase = ((long)b * 257) * 1536 + h * 64;

  for (int ch = tid; ch < 2056; ch += 256) {      // 257 rows x 8 chunks
    int r = ch >> 3, ko = (ch & 7) * 8;
    *(uint4*)&Kl[r * 72 + ko] =
        *(const uint4*)&qkv[qkvbase + 512 + (long)r * 1536 + ko];
  }
  __syncthreads();

  int q0 = qb * 64 + w * 16;
  bf16x8 aq0 = *(const bf16x8*)&qkv[qkvbase + (long)(q0 + c) * 1536 + g * 8];
  bf16x8 aq1 = *(const bf16x8*)&qkv[qkvbase + (long)(q0 + c) * 1536 + 32 + g * 8];

  f32x4 sreg[17];
#pragma unroll
  for (int t = 0; t < 17; ++t) {
    f32x4 a = {0.f, 0.f, 0.f, 0.f};
    a = MFMA(aq0, *(const bf16x8*)&Kl[(t * 16 + c) * 72 + g * 8], a);
    a = MFMA(aq1, *(const bf16x8*)&Kl[(t * 16 + c) * 72 + 32 + g * 8], a);
    sreg[t] = a;
  }

  float mrow[4] = {-1e30f, -1e30f, -1e30f, -1e30f};
#pragma unroll
  for (int t = 0; t < 17; ++t) {
    bool valid = (t * 16 + c) < 257;
#pragma unroll
    for (int q = 0; q < 4; ++q) {
      float v = valid ? sreg[t][q] * 0.125f : -1e30f;
      sreg[t][q] = v;
      mrow[q] = fmaxf(mrow[q], v);
    }
  }
#pragma unroll
  for (int xm = 1; xm < 16; xm <<= 1)
#pragma unroll
    for (int q = 0; q < 4; ++q)
      mrow[q] = fmaxf(mrow[q], __shfl_xor(mrow[q], xm));

  float ssum[4] = {0.f, 0.f, 0.f, 0.f};
#pragma unroll
  for (int t = 0; t < 17; ++t)
#pragma unroll
    for (int q = 0; q < 4; ++q) {
      float e = __expf(sreg[t][q] - mrow[q]);
      sreg[t][q] = e;
      ssum[q] += e;
    }
#pragma unroll
  for (int xm = 1; xm < 16; xm <<= 1)
#pragma unroll
    for (int q = 0; q < 4; ++q) ssum[q] += __shfl_xor(ssum[q], xm);

#pragma unroll
  for (int q = 0; q < 4; ++q) {
    int qg = q0 + g * 4 + q;
    if (qg < 257) {
      float rs = 1.0f / ssum[q];
      long pb = ((long)bh * 272 + qg) * 288;
#pragma unroll
      for (int t = 0; t < 17; ++t)
        P[pb + t * 16 + c] = f2b(sreg[t][q] * rs);
    }
  }
}

// ---------------- attention part B: O = P @ V ------------------------------
__global__ __launch_bounds__(256) void attn_pv_k(const u16* __restrict__ qkv,
                                                 const u16* __restrict__ P,
                                                 u16* __restrict__ o) {
  __shared__ u16 Vt[64 * 296];
  int bx = blockIdx.x;
  int bh = bx / 5, qb = bx % 5;
  int b = bh >> 3, h = bh & 7;
  int tid = threadIdx.x, w = tid >> 6, l = tid & 63, g = l >> 4, c = l & 15;
  long vbase = ((long)b * 257) * 1536 + h * 64 + 1024;

  for (int e = tid; e < 16448; e += 256) {   // V^T stage: Vt[d][k]
    int r = e >> 6, d = e & 63;
    Vt[d * 296 + r] = qkv[vbase + (long)r * 1536 + d];
  }
  for (int e = tid; e < 64 * 39; e += 256) { // zero k in [257,296)
    int d = e / 39, k = 257 + (e - d * 39);
    Vt[d * 296 + k] = 0;
  }
  __syncthreads();

  int q0 = qb * 64 + w * 16;
  int arow = q0 + c;
  if (arow > 271) arow = 271;                 // clamp; garbage rows discarded
  long pbase = ((long)bh * 272 + arow) * 288;

  f32x4 zero = {0.f, 0.f, 0.f, 0.f};
  f32x4 oacc[4] = {zero, zero, zero, zero};
#pragma unroll
  for (int ch = 0; ch < 9; ++ch) {
    bf16x8 ap = *(const bf16x8*)&P[pbase + ch * 32 + g * 8];
#pragma unroll
    for (int dt = 0; dt < 4; ++dt) {
      bf16x8 bv = *(const bf16x8*)&Vt[(dt * 16 + c) * 296 + ch * 32 + g * 8];
      oacc[dt] = MFMA(ap, bv, oacc[dt]);
    }
  }
#pragma unroll
  for (int dt = 0; dt < 4; ++dt)
#pragma unroll
    for (int q = 0; q < 4; ++q) {
      int qg = q0 + g * 4 + q;
      if (qg < 257)
        o[((long)b * 257 + qg) * 512 + h * 64 + dt * 16 + c] = f2b(oacc[dt][q]);
    }
}

// ---------------- vis_mask ones (float32 1.0 at float offset 8421376) ------
__global__ __launch_bounds__(256) void mask_k(float* __restrict__ out) {
  int i = blockIdx.x * 256 + threadIdx.x;
  if (i < 16448) out[8421376 + i] = 1.0f;
}

// ---------------------------------------------------------------------------
extern "C" void kernel_launch(void* const* d_in, const int* in_sizes, int n_in,
                              void* d_out, int out_size, void* d_ws, size_t ws_size,
                              hipStream_t stream) {
  const float* pix     = (const float*)d_in[0];
  const float* patch_w = (const float*)d_in[1];
  const float* patch_b = (const float*)d_in[2];
  const float* row_emb = (const float*)d_in[3];
  const float* col_emb = (const float*)d_in[4];
  const float* clsv    = (const float*)d_in[5];
  const float* ln1_s   = (const float*)d_in[6];
  const float* ln1_b   = (const float*)d_in[7];
  const float* qkv_w   = (const float*)d_in[8];
  const float* qkv_b   = (const float*)d_in[9];
  const float* out_w   = (const float*)d_in[10];
  const float* out_b   = (const float*)d_in[11];
  const float* ln2_s   = (const float*)d_in[12];
  const float* ln2_b   = (const float*)d_in[13];
  const float* mlp_w1  = (const float*)d_in[14];
  const float* mlp_b1  = (const float*)d_in[15];
  const float* mlp_w2  = (const float*)d_in[16];
  const float* mlp_b2  = (const float*)d_in[17];
  const float* lnf_s   = (const float*)d_in[18];
  const float* lnf_b   = (const float*)d_in[19];
  const float* br_w1   = (const float*)d_in[20];
  const float* br_b1   = (const float*)d_in[21];
  const float* br_w2   = (const float*)d_in[22];
  const float* br_b2   = (const float*)d_in[23];
  const float* brln_s  = (const float*)d_in[24];
  const float* brln_b  = (const float*)d_in[25];
  (void)in_sizes; (void)n_in; (void)out_size; (void)ws_size;

  char* ws = (char*)d_ws;
  float* xF   = (float*)(ws);                       // [16640][512] f32
  u16*   nB   = (u16*)(ws + 34078720ull);           // [16640][512] bf16
  u16*   qkvB = (u16*)(ws + 51118080ull);           // [16640][1536] bf16
  u16*   oB   = (u16*)(ws + 102236160ull);          // [16640][512] bf16
  u16*   hB   = (u16*)(ws + 119275520ull);          // [16640][2048] bf16 / P / patA
  u16*   wt   = (u16*)(ws + 199491584ull);          // transposed weights
  u16* wtPatch = wt;
  u16* wtQkv   = wtPatch + 393216;
  u16* wtOut   = wtQkv + 4718592;
  u16* wtM1    = wtOut + 1572864;
  u16* wtM2    = wtM1 + 6291456;
  u16* wtB1    = wtM2 + 6291456;
  u16* wtB2    = wtB1 + 524288;
  u16*   patA = hB;
  u16*   Pbuf = hB;
  float* brF  = (float*)qkvB;

  dim3 blk(256);
  transp_k<<<dim3(16, 24, 1), blk, 0, stream>>>(patch_w, wtPatch, 768, 512);
  transp_k<<<dim3(48, 16, 6), blk, 0, stream>>>(qkv_w, wtQkv, 512, 1536);
  transp_k<<<dim3(16, 16, 6), blk, 0, stream>>>(out_w, wtOut, 512, 512);
  transp_k<<<dim3(64, 16, 6), blk, 0, stream>>>(mlp_w1, wtM1, 512, 2048);
  transp_k<<<dim3(16, 64, 6), blk, 0, stream>>>(mlp_w2, wtM2, 2048, 512);
  transp_k<<<dim3(32, 16, 1), blk, 0, stream>>>(br_w1, wtB1, 512, 1024);
  transp_k<<<dim3(16, 32, 1), blk, 0, stream>>>(br_w2, wtB2, 1024, 512);

  patchify_k<<<49152, blk, 0, stream>>>(pix, patA);
  cls_k<<<128, blk, 0, stream>>>(clsv, xF);
  gemm_k<0><<<dim3(4, 128), blk, 0, stream>>>(patA, wtPatch, patch_b, nullptr,
                                              xF, nullptr, 512, 768, 16384,
                                              row_emb, col_emb);

  for (int l = 0; l < 6; ++l) {
    ln_k<0><<<4112, blk, 0, stream>>>(xF, ln1_s + l * 512, ln1_b + l * 512, nB, nullptr);
    gemm_k<1><<<dim3(12, 129), blk, 0, stream>>>(nB, wtQkv + (size_t)l * 786432,
                                                 qkv_b + l * 1536, nullptr,
                                                 nullptr, qkvB, 1536, 512, 16448,
                                                 nullptr, nullptr);
    attn_scores_k<<<2560, blk, 0, stream>>>(qkvB, Pbuf);
    attn_pv_k<<<2560, blk, 0, stream>>>(qkvB, Pbuf, oB);
    gemm_k<2><<<dim3(4, 129), blk, 0, stream>>>(oB, wtOut + (size_t)l * 262144,
                                                out_b + l * 512, xF, xF, nullptr,
                                                512, 512, 16448, nullptr, nullptr);
    ln_k<0><<<4112, blk, 0, stream>>>(xF, ln2_s + l * 512, ln2_b + l * 512, nB, nullptr);
    gemm_k<3><<<dim3(16, 129), blk, 0, stream>>>(nB, wtM1 + (size_t)l * 1048576,
                                                 mlp_b1 + l * 2048, nullptr,
                                                 nullptr, hB, 2048, 512, 16448,
                                                 nullptr, nullptr);
    gemm_k<2><<<dim3(4, 129), blk, 0, stream>>>(hB, wtM2 + (size_t)l * 1048576,
                                                mlp_b2 + l * 512, xF, xF, nullptr,
                                                512, 2048, 16448, nullptr, nullptr);
  }

  ln_k<0><<<4112, blk, 0, stream>>>(xF, lnf_s, lnf_b, nB, nullptr);
  gemm_k<3><<<dim3(8, 129), blk, 0, stream>>>(nB, wtB1, br_b1, nullptr, nullptr,
                                              hB, 1024, 512, 16448, nullptr, nullptr);
  gemm_k<4><<<dim3(4, 129), blk, 0, stream>>>(hB, wtB2, br_b2, nullptr, brF,
                                              nullptr, 512, 1024, 16448, nullptr,
                                              nullptr);
  ln_k<1><<<4112, blk, 0, stream>>>(brF, brln_s, brln_b, nullptr, (float*)d_out);
  mask_k<<<65, blk, 0, stream>>>((float*)d_out);
}

// Round 9
// 2335.675 us; speedup vs baseline: 1.0662x; 1.0662x over previous
//
#include <hip/hip_runtime.h>
#include <cstdint>

typedef unsigned short u16;
typedef unsigned int   u32;

typedef short bf16x8 __attribute__((ext_vector_type(8)));
typedef float f32x4  __attribute__((ext_vector_type(4)));

#define MFMA(a,b,c) __builtin_amdgcn_mfma_f32_16x16x32_bf16(a,b,c,0,0,0)

// async global->LDS, 16B per lane: LDS dest = wave-uniform base + lane*16,
// global src = per-lane address (guide §5, m97/m104)
#define GLD16(g, s) __builtin_amdgcn_global_load_lds(                      \
    (const __attribute__((address_space(1))) void*)(g),                    \
    (__attribute__((address_space(3))) void*)(s), 16, 0, 0)

__device__ __forceinline__ u16 f2b(float f) {
  u32 u = __float_as_uint(f);
  u += 0x7FFFu + ((u >> 16) & 1u);
  return (u16)(u >> 16);
}

// ---------------- weight transpose + cast: W[K][N] f32 -> WT[N][K] bf16 ----
__global__ __launch_bounds__(256) void transp_k(const float* __restrict__ W,
                                                u16* __restrict__ WT, int K, int N) {
  __shared__ float t[32][33];
  int tx = threadIdx.x & 31, ty = threadIdx.x >> 5;
  long bo = (long)blockIdx.z * K * N;
  int n0 = blockIdx.x * 32, k0 = blockIdx.y * 32;
  const float* Wp = W + bo;
  u16* Tp = WT + bo;
#pragma unroll
  for (int i = 0; i < 32; i += 8)
    t[ty + i][tx] = Wp[(long)(k0 + ty + i) * N + n0 + tx];
  __syncthreads();
#pragma unroll
  for (int i = 0; i < 32; i += 8)
    Tp[(long)(n0 + ty + i) * K + k0 + tx] = f2b(t[tx][ty + i]);
}

// ---------------- patchify: pixels -> patA[16384][768] bf16 ----------------
__global__ __launch_bounds__(256) void patchify_k(const float* __restrict__ pix,
                                                  u16* __restrict__ patA) {
  int idx = blockIdx.x * 256 + threadIdx.x;        // 12,582,912 total (exact)
  int x = idx & 1023;
  int y = (idx >> 10) & 63;
  int c = (idx >> 16) % 3;
  int b = idx / 196608;
  int p  = ((y >> 4) << 6) | (x >> 4);             // ph*64 + pw
  int ci = (c << 8) | ((y & 15) << 4) | (x & 15);  // c*256 + py*16 + px
  patA[(long)(b * 256 + p) * 768 + ci] = f2b(pix[idx]);
}

// ---------------- cls row fill ---------------------------------------------
__global__ __launch_bounds__(256) void cls_k(const float* __restrict__ cls,
                                             float* __restrict__ xF) {
  int i = blockIdx.x * 256 + threadIdx.x;          // 32768 total
  int b = i >> 9, n = i & 511;
  xF[(long)(b * 257) * 512 + n] = cls[n];
}

// ---------------- LayerNorm rows of 512: f32 in -> bf16 (OUT=0) / f32 (OUT=1)
template <int OUT>
__global__ __launch_bounds__(256) void ln_k(const float* __restrict__ x,
                                            const float* __restrict__ gm,
                                            const float* __restrict__ bt,
                                            u16* __restrict__ outB,
                                            float* __restrict__ outF) {
  int row = blockIdx.x * 4 + (threadIdx.x >> 6);
  int l = threadIdx.x & 63;
  const float* xr = x + (long)row * 512 + l * 8;
  float v[8];
  *(float4*)(v)     = *(const float4*)(xr);
  *(float4*)(v + 4) = *(const float4*)(xr + 4);
  float s = 0.f, s2 = 0.f;
#pragma unroll
  for (int j = 0; j < 8; ++j) { s += v[j]; s2 += v[j] * v[j]; }
#pragma unroll
  for (int xm = 1; xm < 64; xm <<= 1) {
    s  += __shfl_xor(s, xm);
    s2 += __shfl_xor(s2, xm);
  }
  float m   = s * (1.f / 512.f);
  float var = fmaxf(s2 * (1.f / 512.f) - m * m, 0.f);
  float rs  = rsqrtf(var + 1e-5f);
  if (OUT == 0) {
    u16 o8[8];
#pragma unroll
    for (int j = 0; j < 8; ++j)
      o8[j] = f2b((v[j] - m) * rs * gm[l * 8 + j] + bt[l * 8 + j]);
    *(uint4*)&outB[(long)row * 512 + l * 8] = *(const uint4*)o8;
  } else {
    float o8[8];
#pragma unroll
    for (int j = 0; j < 8; ++j)
      o8[j] = (v[j] - m) * rs * gm[l * 8 + j] + bt[l * 8 + j];
    float* op = outF + (long)row * 512 + l * 8;
    *(float4*)(op)     = *(const float4*)(o8);
    *(float4*)(op + 4) = *(const float4*)(o8 + 4);
  }
}

// ---------------- GEMM: C[M][N] = A[M][K]bf16 * Bt[N][K]bf16 + epilogue ----
// Double-buffered global_load_lds prefetch (2-phase): stage tile t+1 before
// computing tile t; ONE __syncthreads per K-step (drains vmcnt+lgkm).
// 1-D grid with bijective XCD-chunked swizzle (m204): consecutive work-ids
// (same A-panel, all nt) land on one XCD's L2.
// EPI 0: patch (bias + 2D pos-emb, remap rows, f32 out)
// EPI 1: bias -> bf16 out
// EPI 2: bias + residual -> f32 out
// EPI 3: bias + exact GELU -> bf16 out
// EPI 4: bias -> f32 out
template <int EPI>
__global__ __launch_bounds__(256) void gemm_k(
    const u16* __restrict__ A, const u16* __restrict__ Bt,
    const float* __restrict__ bias, const float* __restrict__ res,
    float* __restrict__ outF, u16* __restrict__ outB,
    int N, int K, int Mreal, int nx,
    const float* __restrict__ aux1, const float* __restrict__ aux2) {
  __shared__ u16 As[2][4096];
  __shared__ u16 Bs[2][4096];
  int tid = threadIdx.x, w = tid >> 6, l = tid & 63, g = l >> 4, c = l & 15;

  // bijective XCD-chunked swizzle (m204)
  int nwg = gridDim.x, bid = blockIdx.x;
  int qd = nwg >> 3, r = nwg & 7;
  int xcd = bid & 7, idx = bid >> 3;
  int swz = (xcd < r ? xcd * (qd + 1) : r * (qd + 1) + (xcd - r) * qd) + idx;
  int mt = swz / nx, nt = swz - mt * nx;

  int wr = (w >> 1) * 64, wc = (w & 1) * 64;
  f32x4 zero = {0.f, 0.f, 0.f, 0.f};
  f32x4 acc[4][4];
#pragma unroll
  for (int m = 0; m < 4; ++m)
#pragma unroll
    for (int n = 0; n < 4; ++n) acc[m][n] = zero;

  // per-lane global element offsets for the two staged chunks
  int c0 = w * 128 + l;
  long gOff0 = (long)(c0 >> 2) * K + (c0 & 3) * 8;
  long gOff1 = (long)((c0 + 64) >> 2) * K + ((c0 + 64) & 3) * 8;
  const u16* Ab = A + (long)(mt * 128) * K;
  const u16* Bb = Bt + (long)(nt * 128) * K;
  int wb = w * 1024;  // wave's chunk base within a buffer (u16 elements)

#define STAGE(buf, kk)                                                     \
  do {                                                                     \
    GLD16(Ab + gOff0 + (kk), &As[buf][wb]);                                \
    GLD16(Ab + gOff1 + (kk), &As[buf][wb + 512]);                          \
    GLD16(Bb + gOff0 + (kk), &Bs[buf][wb]);                                \
    GLD16(Bb + gOff1 + (kk), &Bs[buf][wb + 512]);                          \
  } while (0)

  int NTk = K >> 5;
  STAGE(0, 0);
  __syncthreads();                     // buf0 staged & visible
  int cur = 0;
  for (int t = 0; t < NTk; ++t) {
    if (t + 1 < NTk) STAGE(cur ^ 1, (t + 1) << 5);   // issue early: overlaps
    bf16x8 af[4], bfr[4];
#pragma unroll
    for (int m = 0; m < 4; ++m)
      af[m] = *(const bf16x8*)&As[cur][(wr + m * 16 + c) * 32 + g * 8];
#pragma unroll
    for (int n = 0; n < 4; ++n)
      bfr[n] = *(const bf16x8*)&Bs[cur][(wc + n * 16 + c) * 32 + g * 8];
#pragma unroll
    for (int m = 0; m < 4; ++m)
#pragma unroll
      for (int n = 0; n < 4; ++n)
        acc[m][n] = MFMA(af[m], bfr[n], acc[m][n]);
    __syncthreads();                   // drains prefetch; protects buf reuse
    cur ^= 1;
  }
#undef STAGE

  long Nl = N;
#pragma unroll
  for (int m = 0; m < 4; ++m) {
    int rbase = mt * 128 + wr + m * 16 + g * 4;
#pragma unroll
    for (int n = 0; n < 4; ++n) {
      int col = nt * 128 + wc + n * 16 + c;
      float bv = bias[col];
#pragma unroll
      for (int q = 0; q < 4; ++q) {
        int row = rbase + q;
        if (row >= Mreal) continue;
        float v = acc[m][n][q] + bv;
        if (EPI == 0) {
          int pb = row >> 8, p = row & 255;
          float pos = (col < 256) ? aux1[(p >> 6) * 256 + col]
                                  : aux2[(p & 63) * 256 + col - 256];
          outF[(long)(pb * 257 + 1 + p) * 512 + col] = v + pos;
        } else if (EPI == 1) {
          outB[(long)row * Nl + col] = f2b(v);
        } else if (EPI == 2) {
          outF[(long)row * Nl + col] = res[(long)row * Nl + col] + v;
        } else if (EPI == 3) {
          float gv = v * 0.5f * (1.0f + erff(v * 0.70710678118f));
          outB[(long)row * Nl + col] = f2b(gv);
        } else {
          outF[(long)row * Nl + col] = v;
        }
      }
    }
  }
}

// ---------------- attention part A: scores + softmax -> P ------------------
// grid: (B*NH)*5 blocks; block 256 (4 waves, 16 q-rows each)
// P layout: [bh][272 q][288 k] bf16
__global__ __launch_bounds__(256) void attn_scores_k(const u16* __restrict__ qkv,
                                                     u16* __restrict__ P) {
  __shared__ u16 Kl[272 * 72];
  int bx = blockIdx.x;
  int bh = bx / 5, qb = bx % 5;
  int b = bh >> 3, h = bh & 7;
  int tid = threadIdx.x, w = tid >> 6, l = tid & 63, g = l >> 4, c = l & 15;
  long qkvbase = ((long)b * 257) * 1536 + h * 64;

  for (int ch = tid; ch < 2056; ch += 256) {      // 257 rows x 8 chunks
    int r = ch >> 3, ko = (ch & 7) * 8;
    *(uint4*)&Kl[r * 72 + ko] =
        *(const uint4*)&qkv[qkvbase + 512 + (long)r * 1536 + ko];
  }
  __syncthreads();

  int q0 = qb * 64 + w * 16;
  bf16x8 aq0 = *(const bf16x8*)&qkv[qkvbase + (long)(q0 + c) * 1536 + g * 8];
  bf16x8 aq1 = *(const bf16x8*)&qkv[qkvbase + (long)(q0 + c) * 1536 + 32 + g * 8];

  f32x4 sreg[17];
#pragma unroll
  for (int t = 0; t < 17; ++t) {
    f32x4 a = {0.f, 0.f, 0.f, 0.f};
    a = MFMA(aq0, *(const bf16x8*)&Kl[(t * 16 + c) * 72 + g * 8], a);
    a = MFMA(aq1, *(const bf16x8*)&Kl[(t * 16 + c) * 72 + 32 + g * 8], a);
    sreg[t] = a;
  }

  float mrow[4] = {-1e30f, -1e30f, -1e30f, -1e30f};
#pragma unroll
  for (int t = 0; t < 17; ++t) {
    bool valid = (t * 16 + c) < 257;
#pragma unroll
    for (int q = 0; q < 4; ++q) {
      float v = valid ? sreg[t][q] * 0.125f : -1e30f;
      sreg[t][q] = v;
      mrow[q] = fmaxf(mrow[q], v);
    }
  }
#pragma unroll
  for (int xm = 1; xm < 16; xm <<= 1)
#pragma unroll
    for (int q = 0; q < 4; ++q)
      mrow[q] = fmaxf(mrow[q], __shfl_xor(mrow[q], xm));

  float ssum[4] = {0.f, 0.f, 0.f, 0.f};
#pragma unroll
  for (int t = 0; t < 17; ++t)
#pragma unroll
    for (int q = 0; q < 4; ++q) {
      float e = __expf(sreg[t][q] - mrow[q]);
      sreg[t][q] = e;
      ssum[q] += e;
    }
#pragma unroll
  for (int xm = 1; xm < 16; xm <<= 1)
#pragma unroll
    for (int q = 0; q < 4; ++q) ssum[q] += __shfl_xor(ssum[q], xm);

#pragma unroll
  for (int q = 0; q < 4; ++q) {
    int qg = q0 + g * 4 + q;
    if (qg < 257) {
      float rs = 1.0f / ssum[q];
      long pb = ((long)bh * 272 + qg) * 288;
#pragma unroll
      for (int t = 0; t < 17; ++t)
        P[pb + t * 16 + c] = f2b(sreg[t][q] * rs);
    }
  }
}

// ---------------- attention part B: O = P @ V ------------------------------
__global__ __launch_bounds__(256) void attn_pv_k(const u16* __restrict__ qkv,
                                                 const u16* __restrict__ P,
                                                 u16* __restrict__ o) {
  __shared__ u16 Vt[64 * 296];
  int bx = blockIdx.x;
  int bh = bx / 5, qb = bx % 5;
  int b = bh >> 3, h = bh & 7;
  int tid = threadIdx.x, w = tid >> 6, l = tid & 63, g = l >> 4, c = l & 15;
  long vbase = ((long)b * 257) * 1536 + h * 64 + 1024;

  for (int e = tid; e < 16448; e += 256) {   // V^T stage: Vt[d][k]
    int r = e >> 6, d = e & 63;
    Vt[d * 296 + r] = qkv[vbase + (long)r * 1536 + d];
  }
  for (int e = tid; e < 64 * 39; e += 256) { // zero k in [257,296)
    int d = e / 39, k = 257 + (e - d * 39);
    Vt[d * 296 + k] = 0;
  }
  __syncthreads();

  int q0 = qb * 64 + w * 16;
  int arow = q0 + c;
  if (arow > 271) arow = 271;                 // clamp; garbage rows discarded
  long pbase = ((long)bh * 272 + arow) * 288;

  f32x4 zero = {0.f, 0.f, 0.f, 0.f};
  f32x4 oacc[4] = {zero, zero, zero, zero};
#pragma unroll
  for (int ch = 0; ch < 9; ++ch) {
    bf16x8 ap = *(const bf16x8*)&P[pbase + ch * 32 + g * 8];
#pragma unroll
    for (int dt = 0; dt < 4; ++dt) {
      bf16x8 bv = *(const bf16x8*)&Vt[(dt * 16 + c) * 296 + ch * 32 + g * 8];
      oacc[dt] = MFMA(ap, bv, oacc[dt]);
    }
  }
#pragma unroll
  for (int dt = 0; dt < 4; ++dt)
#pragma unroll
    for (int q = 0; q < 4; ++q) {
      int qg = q0 + g * 4 + q;
      if (qg < 257)
        o[((long)b * 257 + qg) * 512 + h * 64 + dt * 16 + c] = f2b(oacc[dt][q]);
    }
}

// ---------------- vis_mask ones (float32 1.0 at float offset 8421376) ------
__global__ __launch_bounds__(256) void mask_k(float* __restrict__ out) {
  int i = blockIdx.x * 256 + threadIdx.x;
  if (i < 16448) out[8421376 + i] = 1.0f;
}

// ---------------------------------------------------------------------------
extern "C" void kernel_launch(void* const* d_in, const int* in_sizes, int n_in,
                              void* d_out, int out_size, void* d_ws, size_t ws_size,
                              hipStream_t stream) {
  const float* pix     = (const float*)d_in[0];
  const float* patch_w = (const float*)d_in[1];
  const float* patch_b = (const float*)d_in[2];
  const float* row_emb = (const float*)d_in[3];
  const float* col_emb = (const float*)d_in[4];
  const float* clsv    = (const float*)d_in[5];
  const float* ln1_s   = (const float*)d_in[6];
  const float* ln1_b   = (const float*)d_in[7];
  const float* qkv_w   = (const float*)d_in[8];
  const float* qkv_b   = (const float*)d_in[9];
  const float* out_w   = (const float*)d_in[10];
  const float* out_b   = (const float*)d_in[11];
  const float* ln2_s   = (const float*)d_in[12];
  const float* ln2_b   = (const float*)d_in[13];
  const float* mlp_w1  = (const float*)d_in[14];
  const float* mlp_b1  = (const float*)d_in[15];
  const float* mlp_w2  = (const float*)d_in[16];
  const float* mlp_b2  = (const float*)d_in[17];
  const float* lnf_s   = (const float*)d_in[18];
  const float* lnf_b   = (const float*)d_in[19];
  const float* br_w1   = (const float*)d_in[20];
  const float* br_b1   = (const float*)d_in[21];
  const float* br_w2   = (const float*)d_in[22];
  const float* br_b2   = (const float*)d_in[23];
  const float* brln_s  = (const float*)d_in[24];
  const float* brln_b  = (const float*)d_in[25];
  (void)in_sizes; (void)n_in; (void)out_size; (void)ws_size;

  char* ws = (char*)d_ws;
  float* xF   = (float*)(ws);                       // [16640][512] f32
  u16*   nB   = (u16*)(ws + 34078720ull);           // [16640][512] bf16
  u16*   qkvB = (u16*)(ws + 51118080ull);           // [16640][1536] bf16
  u16*   oB   = (u16*)(ws + 102236160ull);          // [16640][512] bf16
  u16*   hB   = (u16*)(ws + 119275520ull);          // [16640][2048] bf16 / P / patA
  u16*   wt   = (u16*)(ws + 199491584ull);          // transposed weights
  u16* wtPatch = wt;
  u16* wtQkv   = wtPatch + 393216;
  u16* wtOut   = wtQkv + 4718592;
  u16* wtM1    = wtOut + 1572864;
  u16* wtM2    = wtM1 + 6291456;
  u16* wtB1    = wtM2 + 6291456;
  u16* wtB2    = wtB1 + 524288;
  u16*   patA = hB;
  u16*   Pbuf = hB;
  float* brF  = (float*)qkvB;

  dim3 blk(256);
  transp_k<<<dim3(16, 24, 1), blk, 0, stream>>>(patch_w, wtPatch, 768, 512);
  transp_k<<<dim3(48, 16, 6), blk, 0, stream>>>(qkv_w, wtQkv, 512, 1536);
  transp_k<<<dim3(16, 16, 6), blk, 0, stream>>>(out_w, wtOut, 512, 512);
  transp_k<<<dim3(64, 16, 6), blk, 0, stream>>>(mlp_w1, wtM1, 512, 2048);
  transp_k<<<dim3(16, 64, 6), blk, 0, stream>>>(mlp_w2, wtM2, 2048, 512);
  transp_k<<<dim3(32, 16, 1), blk, 0, stream>>>(br_w1, wtB1, 512, 1024);
  transp_k<<<dim3(16, 32, 1), blk, 0, stream>>>(br_w2, wtB2, 1024, 512);

  patchify_k<<<49152, blk, 0, stream>>>(pix, patA);
  cls_k<<<128, blk, 0, stream>>>(clsv, xF);
  gemm_k<0><<<512, blk, 0, stream>>>(patA, wtPatch, patch_b, nullptr,
                                     xF, nullptr, 512, 768, 16384, 4,
                                     row_emb, col_emb);

  for (int l = 0; l < 6; ++l) {
    ln_k<0><<<4112, blk, 0, stream>>>(xF, ln1_s + l * 512, ln1_b + l * 512, nB, nullptr);
    gemm_k<1><<<1548, blk, 0, stream>>>(nB, wtQkv + (size_t)l * 786432,
                                        qkv_b + l * 1536, nullptr,
                                        nullptr, qkvB, 1536, 512, 16448, 12,
                                        nullptr, nullptr);
    attn_scores_k<<<2560, blk, 0, stream>>>(qkvB, Pbuf);
    attn_pv_k<<<2560, blk, 0, stream>>>(qkvB, Pbuf, oB);
    gemm_k<2><<<516, blk, 0, stream>>>(oB, wtOut + (size_t)l * 262144,
                                       out_b + l * 512, xF, xF, nullptr,
                                       512, 512, 16448, 4, nullptr, nullptr);
    ln_k<0><<<4112, blk, 0, stream>>>(xF, ln2_s + l * 512, ln2_b + l * 512, nB, nullptr);
    gemm_k<3><<<2064, blk, 0, stream>>>(nB, wtM1 + (size_t)l * 1048576,
                                        mlp_b1 + l * 2048, nullptr,
                                        nullptr, hB, 2048, 512, 16448, 16,
                                        nullptr, nullptr);
    gemm_k<2><<<516, blk, 0, stream>>>(hB, wtM2 + (size_t)l * 1048576,
                                       mlp_b2 + l * 512, xF, xF, nullptr,
                                       512, 2048, 16448, 4, nullptr, nullptr);
  }

  ln_k<0><<<4112, blk, 0, stream>>>(xF, lnf_s, lnf_b, nB, nullptr);
  gemm_k<3><<<1032, blk, 0, stream>>>(nB, wtB1, br_b1, nullptr, nullptr,
                                      hB, 1024, 512, 16448, 8, nullptr, nullptr);
  gemm_k<4><<<516, blk, 0, stream>>>(hB, wtB2, br_b2, nullptr, brF,
                                     nullptr, 512, 1024, 16448, 4, nullptr,
                                     nullptr);
  ln_k<1><<<4112, blk, 0, stream>>>(brF, brln_s, brln_b, nullptr, (float*)d_out);
  mask_k<<<65, blk, 0, stream>>>((float*)d_out);
}